// Round 5
// baseline (1393.443 us; speedup 1.0000x reference)
//
#include <hip/hip_runtime.h>

static constexpr int N = 100000;
static constexpr int E = 3200000;
static constexpr int NFEAT = 512;
static constexpr int K = 10;
static constexpr int NB = (N + 63) / 64;  // 64-node dst buckets

typedef _Float16 half8 __attribute__((ext_vector_type(8)));
typedef _Float16 half4v __attribute__((ext_vector_type(4)));

// ---- workspace layout (bytes) ----
static constexpr size_t OFF_CNT    = 0;                               // N int
static constexpr size_t OFF_BCUR   = 512ull * 1024;                   // NB int (bucket cursors)
static constexpr size_t OFF_ROWPTR = 1024ull * 1024;                  // N+1 int
static constexpr size_t OFF_DINV   = 1536ull * 1024;                  // N float
static constexpr size_t OFF_BSUM   = 2048ull * 1024;                  // 128 int
static constexpr size_t OFF_EW     = 2560ull * 1024;                  // E int = 12.8 MB
static constexpr size_t OFF_GA     = OFF_EW + (size_t)E * 4 + 1024;   // N*64 fp16
static constexpr size_t OFF_GB     = OFF_GA + (size_t)N * 64 * 2 + 1024;
static constexpr size_t OFF_H1     = OFF_GB + (size_t)N * 64 * 2 + 1024;  // N*64 f32
// packed edge buffer (E int, 12.8MB) aliases H1: fill completes before gemm1.

// ---------- degree count ----------
__global__ __launch_bounds__(256) void count_k(const int* __restrict__ dst,
                                               int* __restrict__ cnt) {
  int e = blockIdx.x * 256 + threadIdx.x;
  if (e < E) atomicAdd(&cnt[__builtin_nontemporal_load(dst + e)], 1);
}

__global__ __launch_bounds__(256) void dinv_k(const int* __restrict__ cnt,
                                              float* __restrict__ dinv) {
  int i = blockIdx.x * 256 + threadIdx.x;
  if (i < N) dinv[i] = 1.0f / sqrtf((float)(cnt[i] + 1));  // +1 self-loop
}

// ---------- exclusive scan (3 kernels) ----------
__device__ inline int wave_incl_scan(int x) {
  int lane = threadIdx.x & 63;
#pragma unroll
  for (int off = 1; off < 64; off <<= 1) {
    int y = __shfl_up(x, off, 64);
    if (lane >= off) x += y;
  }
  return x;
}

__global__ __launch_bounds__(256) void scan1_k(const int* __restrict__ cnt,
                                               int* __restrict__ rowptr,
                                               int* __restrict__ bsum) {
  __shared__ int wsum[4];
  int tid = threadIdx.x, wid = tid >> 6, lane = tid & 63;
  int base = blockIdx.x * 1024 + tid * 4;
  int4 v = {0, 0, 0, 0};
  if (base + 3 < N) {
    v = *(const int4*)(cnt + base);
  } else {
    if (base + 0 < N) v.x = cnt[base + 0];
    if (base + 1 < N) v.y = cnt[base + 1];
    if (base + 2 < N) v.z = cnt[base + 2];
    if (base + 3 < N) v.w = cnt[base + 3];
  }
  int tsum = v.x + v.y + v.z + v.w;
  int incl = wave_incl_scan(tsum);
  if (lane == 63) wsum[wid] = incl;
  __syncthreads();
  int wof = 0;
  for (int i = 0; i < wid; ++i) wof += wsum[i];
  int e0 = wof + incl - tsum;  // exclusive start for this thread
  if (base + 0 < N) rowptr[base + 0] = e0;
  if (base + 1 < N) rowptr[base + 1] = e0 + v.x;
  if (base + 2 < N) rowptr[base + 2] = e0 + v.x + v.y;
  if (base + 3 < N) rowptr[base + 3] = e0 + v.x + v.y + v.z;
  if (tid == 255) bsum[blockIdx.x] = wof + incl;  // block total
}

__global__ __launch_bounds__(128) void scan2_k(int* __restrict__ bsum) {
  __shared__ int w0sum;
  int tid = threadIdx.x, wid = tid >> 6, lane = tid & 63;
  int v = (tid < 98) ? bsum[tid] : 0;
  int incl = wave_incl_scan(v);
  if (wid == 0 && lane == 63) w0sum = incl;
  __syncthreads();
  int excl = incl - v + (wid ? w0sum : 0);
  if (tid < 98) bsum[tid] = excl;
}

__global__ __launch_bounds__(256) void scan3_k(int* __restrict__ rowptr,
                                               const int* __restrict__ bsum) {
  int i = blockIdx.x * 256 + threadIdx.x;
  if (i < N) rowptr[i] += bsum[blockIdx.x >> 2];
  if (i == 0) rowptr[N] = E;
}

// ---------- fill phase 0: bucket cursors = rowptr[b*64] ----------
__global__ __launch_bounds__(256) void binit_k(const int* __restrict__ rowptr,
                                               int* __restrict__ bcur) {
  int b = blockIdx.x * 256 + threadIdx.x;
  if (b < NB) bcur[b] = rowptr[b * 64];
}

// ---------- fill phase 1: bucket scatter ----------
// pos allocated densely per 64-node-dst bucket -> packed[] lines receive 16
// sequential writes each (any XCD; byte-masked writeback merges correctly).
__global__ __launch_bounds__(256) void fillp1_k(const int* __restrict__ src,
                                                const int* __restrict__ dst,
                                                int* __restrict__ bcur,
                                                int* __restrict__ packed) {
  int e = blockIdx.x * 256 + threadIdx.x;
  if (e >= E) return;
  int d = __builtin_nontemporal_load(dst + e);
  int s = __builtin_nontemporal_load(src + e);
  int b = d >> 6;
  int pos = atomicAdd(&bcur[b], 1);
  packed[pos] = (s << 6) | (d & 63);
}

// ---------- fill phase 2: per-bucket counting sort -> exact CSR ----------
// One block per bucket; bucket segment [rowptr[b*64], rowptr[min(b*64+64,N)])
// is contiguous (~8KB). Two streaming reads; es writes land inside the same
// 8KB region -> lines fully merge in the local L2.
__global__ __launch_bounds__(256) void fillp2_k(const int* __restrict__ rowptr,
                                                const int* __restrict__ packed,
                                                int* __restrict__ es) {
  __shared__ int cl[64];    // per-dst-local counts -> cursors
  const int b = blockIdx.x;
  const int n0 = b * 64;
  const int base = rowptr[n0];
  const int end = (n0 + 64 <= N) ? rowptr[n0 + 64] : E;
  const int tid = threadIdx.x;
  if (tid < 64) cl[tid] = 0;
  __syncthreads();
  for (int i = base + tid; i < end; i += 256)
    atomicAdd(&cl[packed[i] & 63], 1);
  __syncthreads();
  if (tid == 0) {  // serial exclusive scan of 64 counts -> global cursors
    int run = base;
    for (int j = 0; j < 64; ++j) {
      int c = cl[j];
      cl[j] = run;
      run += c;
    }
  }
  __syncthreads();
  for (int i = base + tid; i < end; i += 256) {
    int p = packed[i];
    int pos = atomicAdd(&cl[p & 63], 1);
    es[pos] = p >> 6;
  }
}

// ---------- GEMM1: h1 = relu(x @ W1 + b1), [N,512]x[512,64] ----------
__global__ __launch_bounds__(256) void gemm1_k(const float* __restrict__ x,
                                               const float* __restrict__ W1,
                                               const float* __restrict__ b1,
                                               float* __restrict__ h1) {
  __shared__ float xs[16][256];   // transposed x tile: xs[k][node]
  __shared__ float w1s[16 * 64];  // W1 tile
  const int tid = threadIdx.x;
  const int n0 = blockIdx.x * 256;
  const int tn = tid & 127;  // node pair: tn, tn+128
  const int jh = tid >> 7;   // j half: [jh*32, jh*32+32)
  float4 acca[8], accb[8];
#pragma unroll
  for (int i = 0; i < 8; ++i) {
    acca[i] = float4{0.f, 0.f, 0.f, 0.f};
    accb[i] = float4{0.f, 0.f, 0.f, 0.f};
  }
  const int rowA = min(n0 + tid, N - 1);
  const float* xr = x + (size_t)rowA * NFEAT;
  for (int k0 = 0; k0 < NFEAT; k0 += 16) {
    float4 a0 = *(const float4*)(xr + k0 + 0);
    float4 a1 = *(const float4*)(xr + k0 + 4);
    float4 a2 = *(const float4*)(xr + k0 + 8);
    float4 a3 = *(const float4*)(xr + k0 + 12);
    float4 wv = *(const float4*)(W1 + (size_t)k0 * 64 + tid * 4);
    __syncthreads();  // previous iteration's reads complete
    xs[0][tid] = a0.x;  xs[1][tid] = a0.y;  xs[2][tid] = a0.z;  xs[3][tid] = a0.w;
    xs[4][tid] = a1.x;  xs[5][tid] = a1.y;  xs[6][tid] = a1.z;  xs[7][tid] = a1.w;
    xs[8][tid] = a2.x;  xs[9][tid] = a2.y;  xs[10][tid] = a2.z; xs[11][tid] = a2.w;
    xs[12][tid] = a3.x; xs[13][tid] = a3.y; xs[14][tid] = a3.z; xs[15][tid] = a3.w;
    *(float4*)&w1s[tid * 4] = wv;
    __syncthreads();
#pragma unroll
    for (int kk = 0; kk < 16; ++kk) {
      float xa = xs[kk][tn];
      float xb = xs[kk][tn + 128];
      const float* wr = &w1s[kk * 64 + jh * 32];
#pragma unroll
      for (int jj = 0; jj < 8; ++jj) {
        float4 w4 = *(const float4*)(wr + jj * 4);
        acca[jj].x += xa * w4.x; acca[jj].y += xa * w4.y;
        acca[jj].z += xa * w4.z; acca[jj].w += xa * w4.w;
        accb[jj].x += xb * w4.x; accb[jj].y += xb * w4.y;
        accb[jj].z += xb * w4.z; accb[jj].w += xb * w4.w;
      }
    }
  }
  const int na = n0 + tn, nb = na + 128;
#pragma unroll
  for (int jj = 0; jj < 8; ++jj) {
    int j = jh * 32 + jj * 4;
    float4 bb = *(const float4*)(b1 + j);
    float4 ra, rb;
    ra.x = fmaxf(acca[jj].x + bb.x, 0.f); ra.y = fmaxf(acca[jj].y + bb.y, 0.f);
    ra.z = fmaxf(acca[jj].z + bb.z, 0.f); ra.w = fmaxf(acca[jj].w + bb.w, 0.f);
    rb.x = fmaxf(accb[jj].x + bb.x, 0.f); rb.y = fmaxf(accb[jj].y + bb.y, 0.f);
    rb.z = fmaxf(accb[jj].z + bb.z, 0.f); rb.w = fmaxf(accb[jj].w + bb.w, 0.f);
    if (na < N) *(float4*)(h1 + (size_t)na * 64 + j) = ra;
    if (nb < N) *(float4*)(h1 + (size_t)nb * 64 + j) = rb;
  }
}

// ---------- GEMM2: h0 = h1@W2 + b2 ; out = temp[0]*h0 ; g0 = dinv*h0 (fp16) --
__global__ __launch_bounds__(256) void gemm2_k(const float* __restrict__ h1,
                                               const float* __restrict__ W2,
                                               const float* __restrict__ b2,
                                               const float* __restrict__ temp,
                                               const float* __restrict__ dinv,
                                               _Float16* __restrict__ g0,
                                               float* __restrict__ out) {
  __shared__ float w2s[64 * 64];
  const int tid = threadIdx.x;
#pragma unroll
  for (int i = 0; i < 4; ++i)
    *(float4*)&w2s[(i * 256 + tid) * 4] = *(const float4*)(W2 + (size_t)(i * 256 + tid) * 4);
  __syncthreads();
  const int node = blockIdx.x * 256 + tid;
  if (node >= N) return;
  float4 acc[16];
#pragma unroll
  for (int c = 0; c < 16; ++c) acc[c] = *(const float4*)(b2 + c * 4);
  const float* hr = h1 + (size_t)node * 64;
  for (int j0 = 0; j0 < 64; j0 += 4) {
    float4 hv = *(const float4*)(hr + j0);
    float hv4[4] = {hv.x, hv.y, hv.z, hv.w};
#pragma unroll
    for (int l = 0; l < 4; ++l) {
      const float* wr = &w2s[(j0 + l) * 64];
#pragma unroll
      for (int c = 0; c < 16; ++c) {
        float4 w4 = *(const float4*)(wr + c * 4);
        acc[c].x += hv4[l] * w4.x; acc[c].y += hv4[l] * w4.y;
        acc[c].z += hv4[l] * w4.z; acc[c].w += hv4[l] * w4.w;
      }
    }
  }
  const float t0 = temp[0];
  const float di = dinv[node];
  _Float16* gp = g0 + (size_t)node * 64;
  float* op = out + (size_t)node * 64;
#pragma unroll
  for (int c = 0; c < 16; ++c) {
    float4 o;
    o.x = t0 * acc[c].x; o.y = t0 * acc[c].y;
    o.z = t0 * acc[c].z; o.w = t0 * acc[c].w;
    *(float4*)(op + c * 4) = o;
    half4v g;
    g[0] = (_Float16)(di * acc[c].x); g[1] = (_Float16)(di * acc[c].y);
    g[2] = (_Float16)(di * acc[c].z); g[3] = (_Float16)(di * acc[c].w);
    *(half4v*)(gp + c * 4) = g;
  }
}

// ---------- propagation with prescaled fp16 state ----------
// g = dinv .* h. h'[i] = dinv[i]*(g[i] + sum_{src} g[src]);
// out += temp*h'; g' = dinv[i]*h'.
// 8 lanes per node (8 fp16 features/lane = 16B), 32 nodes per block.
__global__ __launch_bounds__(256) void prop_k(const _Float16* __restrict__ gin,
                                              _Float16* __restrict__ gout,
                                              float* __restrict__ out,
                                              const int* __restrict__ rowptr,
                                              const int* __restrict__ es,
                                              const float* __restrict__ dinv,
                                              const float* __restrict__ temp,
                                              int kp1, int writeh) {
  const int tid = threadIdx.x;
  const int sub = tid >> 3;                 // node within block's 32
  const int l = tid & 7;                    // feature octet [l*8, l*8+8)
  const int node = blockIdx.x * 32 + sub;   // N % 32 == 0, grid exact
  const int rs = rowptr[node];
  const int re = rowptr[node + 1];
  const float di = dinv[node];
  const _Float16* __restrict__ gq = gin + l * 8;

  // self term: + g[node]
  half8 sr = *(const half8*)(gq + (size_t)node * 64);
  float a0[8], a1[8], a2[8], a3[8];
#pragma unroll
  for (int i = 0; i < 8; ++i) {
    a0[i] = (float)sr[i];
    a1[i] = 0.f; a2[i] = 0.f; a3[i] = 0.f;
  }

  int e = rs;
  for (; e + 8 <= re; e += 8) {
    int s0 = es[e],     s1 = es[e + 1], s2 = es[e + 2], s3 = es[e + 3];
    int s4 = es[e + 4], s5 = es[e + 5], s6 = es[e + 6], s7 = es[e + 7];
    half8 r0 = *(const half8*)(gq + (size_t)s0 * 64);
    half8 r1 = *(const half8*)(gq + (size_t)s1 * 64);
    half8 r2 = *(const half8*)(gq + (size_t)s2 * 64);
    half8 r3 = *(const half8*)(gq + (size_t)s3 * 64);
    half8 r4 = *(const half8*)(gq + (size_t)s4 * 64);
    half8 r5 = *(const half8*)(gq + (size_t)s5 * 64);
    half8 r6 = *(const half8*)(gq + (size_t)s6 * 64);
    half8 r7 = *(const half8*)(gq + (size_t)s7 * 64);
#pragma unroll
    for (int i = 0; i < 8; ++i) {
      a0[i] += (float)r0[i];
      a1[i] += (float)r1[i];
      a2[i] += (float)r2[i];
      a3[i] += (float)r3[i];
      a0[i] += (float)r4[i];
      a1[i] += (float)r5[i];
      a2[i] += (float)r6[i];
      a3[i] += (float)r7[i];
    }
  }
  for (; e + 4 <= re; e += 4) {
    int s0 = es[e], s1 = es[e + 1], s2 = es[e + 2], s3 = es[e + 3];
    half8 r0 = *(const half8*)(gq + (size_t)s0 * 64);
    half8 r1 = *(const half8*)(gq + (size_t)s1 * 64);
    half8 r2 = *(const half8*)(gq + (size_t)s2 * 64);
    half8 r3 = *(const half8*)(gq + (size_t)s3 * 64);
#pragma unroll
    for (int i = 0; i < 8; ++i) {
      a0[i] += (float)r0[i];
      a1[i] += (float)r1[i];
      a2[i] += (float)r2[i];
      a3[i] += (float)r3[i];
    }
  }
  for (; e < re; ++e) {
    int s0 = es[e];
    half8 r0 = *(const half8*)(gq + (size_t)s0 * 64);
#pragma unroll
    for (int i = 0; i < 8; ++i) a0[i] += (float)r0[i];
  }

  float S[8];
#pragma unroll
  for (int i = 0; i < 8; ++i) S[i] = (a0[i] + a1[i]) + (a2[i] + a3[i]);

  const float th = temp[kp1] * di;  // out += temp * h' = temp * di * S
  const float dd = di * di;         // g' = di * h' = di*di * S
  const size_t base = (size_t)node * 64 + l * 8;
  float4 o0 = *(const float4*)(out + base);
  float4 o1 = *(const float4*)(out + base + 4);
  o0.x += th * S[0]; o0.y += th * S[1]; o0.z += th * S[2]; o0.w += th * S[3];
  o1.x += th * S[4]; o1.y += th * S[5]; o1.z += th * S[6]; o1.w += th * S[7];
  *(float4*)(out + base) = o0;
  *(float4*)(out + base + 4) = o1;
  if (writeh) {
    half8 gw;
#pragma unroll
    for (int i = 0; i < 8; ++i) gw[i] = (_Float16)(dd * S[i]);
    *(half8*)(gout + base) = gw;
  }
}

extern "C" void kernel_launch(void* const* d_in, const int* in_sizes, int n_in,
                              void* d_out, int out_size, void* d_ws, size_t ws_size,
                              hipStream_t stream) {
  const float* x = (const float*)d_in[0];
  const int* ei = (const int*)d_in[1];
  const float* W1 = (const float*)d_in[2];
  const float* b1 = (const float*)d_in[3];
  const float* W2 = (const float*)d_in[4];
  const float* b2 = (const float*)d_in[5];
  const float* temp = (const float*)d_in[6];
  const int* srcp = ei;       // edge_index[0]
  const int* dstp = ei + E;   // edge_index[1]

  unsigned char* ws = (unsigned char*)d_ws;
  int* cnt = (int*)(ws + OFF_CNT);
  int* bcur = (int*)(ws + OFF_BCUR);
  int* rowptr = (int*)(ws + OFF_ROWPTR);
  float* dinv = (float*)(ws + OFF_DINV);
  int* bsum = (int*)(ws + OFF_BSUM);
  int* es = (int*)(ws + OFF_EW);
  _Float16* gA = (_Float16*)(ws + OFF_GA);
  _Float16* gB = (_Float16*)(ws + OFF_GB);
  float* h1 = (float*)(ws + OFF_H1);
  int* packed = (int*)(ws + OFF_H1);  // aliases h1: dead once gemm1 runs
  float* out = (float*)d_out;

  hipMemsetAsync(cnt, 0, (size_t)N * 4, stream);

  count_k<<<E / 256, 256, 0, stream>>>(dstp, cnt);
  dinv_k<<<(N + 255) / 256, 256, 0, stream>>>(cnt, dinv);
  scan1_k<<<(N + 1023) / 1024, 256, 0, stream>>>(cnt, rowptr, bsum);
  scan2_k<<<1, 128, 0, stream>>>(bsum);
  scan3_k<<<(N + 255) / 256, 256, 0, stream>>>(rowptr, bsum);
  binit_k<<<(NB + 255) / 256, 256, 0, stream>>>(rowptr, bcur);
  fillp1_k<<<E / 256, 256, 0, stream>>>(srcp, dstp, bcur, packed);
  fillp2_k<<<NB, 256, 0, stream>>>(rowptr, packed, es);

  gemm1_k<<<(N + 255) / 256, 256, 0, stream>>>(x, W1, b1, h1);
  gemm2_k<<<(N + 255) / 256, 256, 0, stream>>>(h1, W2, b2, temp, dinv, gA, out);

  const _Float16* gin = gA;
  _Float16* gout = gB;
  for (int k = 0; k < K; ++k) {
    prop_k<<<N / 32, 256, 0, stream>>>(gin, gout, out, rowptr, es, dinv, temp,
                                       k + 1, (k + 1 < K) ? 1 : 0);
    _Float16* t = (_Float16*)gin;
    gin = gout;
    gout = t;
  }
}